// Round 1
// baseline (612.115 us; speedup 1.0000x reference)
//
#include <hip/hip_runtime.h>

#ifndef N_TOTAL_UNUSED
#endif

// Per-point GICP mahalanobis + mean reduction.
// maha = res^T * inv(RCR) * res  computed as res^T * adj(RCR) * res / det(RCR)
// RCR = C_tar[idx] + T3 * C_src * T3^T  (3x3 symmetric SPD)
__global__ __launch_bounds__(256) void gicp_maha_kernel(
    const float*  __restrict__ T,     // 4x4 row-major
    const float4* __restrict__ src,   // N x (x,y,z,1)
    const float4* __restrict__ tar,   // M x (x,y,z,1)
    const float4* __restrict__ cs,    // N x 4 rows of 4x4 (only 3x3 nonzero)
    const float4* __restrict__ ct,    // M x 4 rows
    const int*    __restrict__ idx,   // N
    double*       __restrict__ accum, // [1]
    int n)
{
    // T is wave-uniform: these become scalar loads through the constant path.
    const float t00 = T[0],  t01 = T[1],  t02 = T[2];
    const float t10 = T[4],  t11 = T[5],  t12 = T[6];
    const float t20 = T[8],  t21 = T[9],  t22 = T[10];
    const float t30 = T[12], t31 = T[13], t32 = T[14];

    float local = 0.0f;
    for (int i = blockIdx.x * blockDim.x + threadIdx.x; i < n;
         i += gridDim.x * blockDim.x) {
        const float4 s  = src[i];
        const int    j  = idx[i];
        const float4 tp = tar[j];

        // transformed_src[c] = sum_r src[r] * T[r][c]  (c = 0..2)
        const float ts0 = s.x * t00 + s.y * t10 + s.z * t20 + s.w * t30;
        const float ts1 = s.x * t01 + s.y * t11 + s.z * t21 + s.w * t31;
        const float ts2 = s.x * t02 + s.y * t12 + s.z * t22 + s.w * t32;
        const float r0 = tp.x - ts0;
        const float r1 = tp.y - ts1;
        const float r2 = tp.z - ts2;

        // C_src 3x3 (rows of the 4x4; row/col 3 are zero by construction)
        const size_t bi = (size_t)i * 4;
        const float4 c0 = cs[bi + 0];
        const float4 c1 = cs[bi + 1];
        const float4 c2 = cs[bi + 2];

        // U = T3 * C   (U[a][k] = sum_j T[a][j] * C[j][k])
        const float u00 = t00*c0.x + t01*c1.x + t02*c2.x;
        const float u01 = t00*c0.y + t01*c1.y + t02*c2.y;
        const float u02 = t00*c0.z + t01*c1.z + t02*c2.z;
        const float u10 = t10*c0.x + t11*c1.x + t12*c2.x;
        const float u11 = t10*c0.y + t11*c1.y + t12*c2.y;
        const float u12 = t10*c0.z + t11*c1.z + t12*c2.z;
        const float u20 = t20*c0.x + t21*c1.x + t22*c2.x;
        const float u21 = t20*c0.y + t21*c1.y + t22*c2.y;
        const float u22 = t20*c0.z + t21*c1.z + t22*c2.z;

        // tcov[a][b] = U[a][:] . T3[b][:]
        const float tc00 = u00*t00 + u01*t01 + u02*t02;
        const float tc01 = u00*t10 + u01*t11 + u02*t12;
        const float tc02 = u00*t20 + u01*t21 + u02*t22;
        const float tc11 = u10*t10 + u11*t11 + u12*t12;
        const float tc12 = u10*t20 + u11*t21 + u12*t22;
        const float tc22 = u20*t20 + u21*t21 + u22*t22;

        // C_tar gather rows 0..2
        const size_t bj = (size_t)j * 4;
        const float4 d0 = ct[bj + 0];
        const float4 d1 = ct[bj + 1];
        const float4 d2 = ct[bj + 2];

        // symmetric RCR = [[a,b,c],[b,d,e],[c,e,f]]
        const float a = d0.x + tc00;
        const float b = d0.y + tc01;
        const float c = d0.z + tc02;
        const float d = d1.y + tc11;
        const float e = d1.z + tc12;
        const float f = d2.z + tc22;

        // adjugate cofactors (symmetric)
        const float A00 = d * f - e * e;
        const float A01 = c * e - b * f;
        const float A02 = b * e - c * d;
        const float A11 = a * f - c * c;
        const float A12 = b * c - a * e;
        const float A22 = a * d - b * b;

        const float det = a * A00 + b * A01 + c * A02;

        const float num = r0 * r0 * A00 + r1 * r1 * A11 + r2 * r2 * A22
                        + 2.0f * (r0 * r1 * A01 + r0 * r2 * A02 + r1 * r2 * A12);

        local += num / det;
    }

    // wave-64 tree reduction, then one f64 atomic per wave
    for (int off = 32; off > 0; off >>= 1)
        local += __shfl_down(local, off, 64);
    if ((threadIdx.x & 63) == 0)
        atomicAdd(accum, (double)local);
}

__global__ void gicp_finalize_kernel(const double* __restrict__ accum,
                                     float* __restrict__ out, double scale)
{
    out[0] = (float)(accum[0] * scale);
}

extern "C" void kernel_launch(void* const* d_in, const int* in_sizes, int n_in,
                              void* d_out, int out_size, void* d_ws, size_t ws_size,
                              hipStream_t stream) {
    const float*  T   = (const float*)d_in[0];
    const float4* src = (const float4*)d_in[1];
    const float4* tar = (const float4*)d_in[2];
    const float4* cs  = (const float4*)d_in[3];
    const float4* ct  = (const float4*)d_in[4];
    const int*    idx = (const int*)d_in[5];
    const int n = in_sizes[1] / 4;  // src_points is (N,4)

    double* accum = (double*)d_ws;
    hipMemsetAsync(d_ws, 0, sizeof(double), stream);  // ws is poisoned each call

    const int block = 256;
    const int grid  = (n + block - 1) / block;
    gicp_maha_kernel<<<grid, block, 0, stream>>>(T, src, tar, cs, ct, idx,
                                                 accum, n);
    gicp_finalize_kernel<<<1, 1, 0, stream>>>(accum, (float*)d_out,
                                              0.5 / (double)n);
}

// Round 2
// 339.281 us; speedup vs baseline: 1.8042x; 1.8042x over previous
//
#include <hip/hip_runtime.h>

#define GRID_BLOCKS 1024
#define BLOCK       256

// Per-point GICP mahalanobis: maha = res^T * adj(RCR) * res / det(RCR)
// RCR = C_tar[idx] + T3 * C_src * T3^T  (3x3 symmetric SPD)
__device__ __forceinline__ float gicp_point(
    int i,
    const float t00, const float t01, const float t02,
    const float t10, const float t11, const float t12,
    const float t20, const float t21, const float t22,
    const float t30, const float t31, const float t32,
    const float4* __restrict__ src, const float4* __restrict__ tar,
    const float4* __restrict__ cs,  const float4* __restrict__ ct,
    const int*    __restrict__ idx)
{
    const float4 s  = src[i];
    const int    j  = idx[i];
    const float4 tp = tar[j];

    const float ts0 = s.x * t00 + s.y * t10 + s.z * t20 + s.w * t30;
    const float ts1 = s.x * t01 + s.y * t11 + s.z * t21 + s.w * t31;
    const float ts2 = s.x * t02 + s.y * t12 + s.z * t22 + s.w * t32;
    const float r0 = tp.x - ts0;
    const float r1 = tp.y - ts1;
    const float r2 = tp.z - ts2;

    const size_t bi = (size_t)i * 4;
    const float4 c0 = cs[bi + 0];
    const float4 c1 = cs[bi + 1];
    const float4 c2 = cs[bi + 2];

    // U = T3 * C
    const float u00 = t00*c0.x + t01*c1.x + t02*c2.x;
    const float u01 = t00*c0.y + t01*c1.y + t02*c2.y;
    const float u02 = t00*c0.z + t01*c1.z + t02*c2.z;
    const float u10 = t10*c0.x + t11*c1.x + t12*c2.x;
    const float u11 = t10*c0.y + t11*c1.y + t12*c2.y;
    const float u12 = t10*c0.z + t11*c1.z + t12*c2.z;
    const float u20 = t20*c0.x + t21*c1.x + t22*c2.x;
    const float u21 = t20*c0.y + t21*c1.y + t22*c2.y;
    const float u22 = t20*c0.z + t21*c1.z + t22*c2.z;

    // tcov = U * T3^T (symmetric part only)
    const float tc00 = u00*t00 + u01*t01 + u02*t02;
    const float tc01 = u00*t10 + u01*t11 + u02*t12;
    const float tc02 = u00*t20 + u01*t21 + u02*t22;
    const float tc11 = u10*t10 + u11*t11 + u12*t12;
    const float tc12 = u10*t20 + u11*t21 + u12*t22;
    const float tc22 = u20*t20 + u21*t21 + u22*t22;

    const size_t bj = (size_t)j * 4;
    const float4 d0 = ct[bj + 0];
    const float4 d1 = ct[bj + 1];
    const float4 d2 = ct[bj + 2];

    const float a = d0.x + tc00;
    const float b = d0.y + tc01;
    const float c = d0.z + tc02;
    const float d = d1.y + tc11;
    const float e = d1.z + tc12;
    const float f = d2.z + tc22;

    const float A00 = d * f - e * e;
    const float A01 = c * e - b * f;
    const float A02 = b * e - c * d;
    const float A11 = a * f - c * c;
    const float A12 = b * c - a * e;
    const float A22 = a * d - b * b;

    const float det = a * A00 + b * A01 + c * A02;

    const float num = r0 * r0 * A00 + r1 * r1 * A11 + r2 * r2 * A22
                    + 2.0f * (r0 * r1 * A01 + r0 * r2 * A02 + r1 * r2 * A12);

    return num / det;
}

__global__ __launch_bounds__(BLOCK) void gicp_maha_kernel(
    const float*  __restrict__ T,
    const float4* __restrict__ src,
    const float4* __restrict__ tar,
    const float4* __restrict__ cs,
    const float4* __restrict__ ct,
    const int*    __restrict__ idx,
    float*        __restrict__ partial,  // [GRID_BLOCKS], each written once
    int n)
{
    const float t00 = T[0],  t01 = T[1],  t02 = T[2];
    const float t10 = T[4],  t11 = T[5],  t12 = T[6];
    const float t20 = T[8],  t21 = T[9],  t22 = T[10];
    const float t30 = T[12], t31 = T[13], t32 = T[14];

    const int stride = GRID_BLOCKS * BLOCK;
    int i = blockIdx.x * BLOCK + threadIdx.x;

    float local = 0.0f;
    // 4-way unrolled grid-stride: 4 independent idx->gather chains in flight
    for (; i + 3 * stride < n; i += 4 * stride) {
        float v0 = gicp_point(i,            t00,t01,t02,t10,t11,t12,t20,t21,t22,t30,t31,t32, src,tar,cs,ct,idx);
        float v1 = gicp_point(i +   stride, t00,t01,t02,t10,t11,t12,t20,t21,t22,t30,t31,t32, src,tar,cs,ct,idx);
        float v2 = gicp_point(i + 2*stride, t00,t01,t02,t10,t11,t12,t20,t21,t22,t30,t31,t32, src,tar,cs,ct,idx);
        float v3 = gicp_point(i + 3*stride, t00,t01,t02,t10,t11,t12,t20,t21,t22,t30,t31,t32, src,tar,cs,ct,idx);
        local += (v0 + v1) + (v2 + v3);
    }
    for (; i < n; i += stride)
        local += gicp_point(i, t00,t01,t02,t10,t11,t12,t20,t21,t22,t30,t31,t32, src,tar,cs,ct,idx);

    // wave-64 reduction
    for (int off = 32; off > 0; off >>= 1)
        local += __shfl_down(local, off, 64);

    __shared__ float wsum[BLOCK / 64];
    const int wave = threadIdx.x >> 6;
    if ((threadIdx.x & 63) == 0) wsum[wave] = local;
    __syncthreads();
    if (threadIdx.x == 0) {
        float s = wsum[0];
        #pragma unroll
        for (int w = 1; w < BLOCK / 64; ++w) s += wsum[w];
        partial[blockIdx.x] = s;   // contention-free: one store per block
    }
}

__global__ __launch_bounds__(256) void gicp_finalize_kernel(
    const float* __restrict__ partial, float* __restrict__ out, double scale)
{
    double s = 0.0;
    for (int k = threadIdx.x; k < GRID_BLOCKS; k += 256)
        s += (double)partial[k];
    for (int off = 32; off > 0; off >>= 1)
        s += __shfl_down(s, off, 64);
    __shared__ double wsum[4];
    const int wave = threadIdx.x >> 6;
    if ((threadIdx.x & 63) == 0) wsum[wave] = s;
    __syncthreads();
    if (threadIdx.x == 0)
        out[0] = (float)((wsum[0] + wsum[1] + wsum[2] + wsum[3]) * scale);
}

extern "C" void kernel_launch(void* const* d_in, const int* in_sizes, int n_in,
                              void* d_out, int out_size, void* d_ws, size_t ws_size,
                              hipStream_t stream) {
    const float*  T   = (const float*)d_in[0];
    const float4* src = (const float4*)d_in[1];
    const float4* tar = (const float4*)d_in[2];
    const float4* cs  = (const float4*)d_in[3];
    const float4* ct  = (const float4*)d_in[4];
    const int*    idx = (const int*)d_in[5];
    const int n = in_sizes[1] / 4;  // src_points is (N,4)

    float* partial = (float*)d_ws;  // GRID_BLOCKS floats, fully overwritten

    gicp_maha_kernel<<<GRID_BLOCKS, BLOCK, 0, stream>>>(T, src, tar, cs, ct,
                                                        idx, partial, n);
    gicp_finalize_kernel<<<1, 256, 0, stream>>>(partial, (float*)d_out,
                                                0.5 / (double)n);
}